// Round 4
// baseline (130.770 us; speedup 1.0000x reference)
//
#include <hip/hip_runtime.h>
#include <math.h>

// Problem constants: B=4, S=2048, D_IN=1024, D_OUT=1024, E=8, K=2
#define TOKENS 8192
#define DIN    1024
#define DOUT   1024
#define NE     8

typedef float vf4 __attribute__((ext_vector_type(4)));

// Butterfly reduction across the 64-lane wave; every lane ends with the full sum.
__device__ __forceinline__ float wredsum(float v) {
#pragma unroll
  for (int off = 32; off > 0; off >>= 1) v += __shfl_xor(v, off, 64);
  return v;
}

// f32 -> bf16 bits, round-to-nearest-even
__device__ __forceinline__ unsigned short f2bf(float f) {
  unsigned int u = __float_as_uint(f);
  return (unsigned short)((u + 0x7FFFu + ((u >> 16) & 1u)) >> 16);
}
__device__ __forceinline__ float bf2f(unsigned short u) {
  return __uint_as_float(((unsigned int)u) << 16);
}

// 512 threads (8 waves), 2 tokens per wave -> 16 tokens/block, 512 blocks.
// LDS: 32 KB f32 gate_w + 32 KB bf16 candidate expert rows = 64 KB
//   -> 2 blocks/CU resident (16 waves/CU), ALL 512 blocks co-resident.
// Only expert rows [e][0][:] and [e][1][:] are reachable (gather uses feature
// index j<K=2), so ALL candidate value rows fit in LDS: no data-dependent
// global fetch remains after the x load.
__global__ __launch_bounds__(512, 4) void moe_fused(
    const float* __restrict__ x,             // [TOKENS][DIN]
    const float* __restrict__ gate_w,        // [NE][DIN]
    const float* __restrict__ gate_b,        // [NE]
    const float* __restrict__ expert_biases, // [NE]
    const float* __restrict__ expert_w,      // [NE][DOUT][DIN]
    const float* __restrict__ expert_b,      // [NE][DOUT]
    float* __restrict__ out,                 // [TOKENS][DOUT]
    float* __restrict__ out_idx) {           // [TOKENS][2] (indices as f32)
  __shared__ float          lgate[NE * DIN];   // 32 KB, f32 (selection must be exact)
  __shared__ unsigned short lexp[16 * DIN];    // 32 KB, bf16: row e = w[e][0][:], row 8+e = w[e][1][:]

  // ---- stage gate_w (2048 vf4) ----
  {
    const vf4* src = (const vf4*)gate_w;
    vf4* dst = (vf4*)lgate;
#pragma unroll
    for (int i = 0; i < 4; ++i)
      dst[threadIdx.x + 512 * i] = src[threadIdx.x + 512 * i];
  }
  // ---- stage 16 candidate expert rows as bf16 (4096 ushort4) ----
  {
    const vf4* src = (const vf4*)expert_w;
    ushort4* dst = (ushort4*)lexp;
#pragma unroll
    for (int k = 0; k < 8; ++k) {
      int flat = threadIdx.x + 512 * k;  // 0..4095 = row*256 + col
      int row = flat >> 8;               // 0..15
      int col = flat & 255;
      int e = row & 7;
      int o = row >> 3;                  // 0 or 1
      vf4 v = src[(size_t)e * (DOUT * DIN / 4) + o * (DIN / 4) + col];
      dst[flat] = make_ushort4(f2bf(v.x), f2bf(v.y), f2bf(v.z), f2bf(v.w));
    }
  }
  __syncthreads();

  const int wid  = blockIdx.x * 8 + (threadIdx.x >> 6);
  const int lane = threadIdx.x & 63;
  const int t0 = wid * 2;
  const int t1 = t0 + 1;

  // ---- load both x rows (coalesced 16B/lane, 16 floats per lane per token) ----
  vf4 xa[4], xb[4];
  const vf4* xr0 = (const vf4*)(x + (size_t)t0 * DIN);
  const vf4* xr1 = (const vf4*)(x + (size_t)t1 * DIN);
#pragma unroll
  for (int i = 0; i < 4; ++i) {
    xa[i] = xr0[lane + 64 * i];
    xb[i] = xr1[lane + 64 * i];
  }

  // ---- gate logits: 8 dots per token; each LDS weight read feeds 2 tokens ----
  float za[NE], zb[NE];
#pragma unroll
  for (int e = 0; e < NE; ++e) { za[e] = 0.f; zb[e] = 0.f; }
#pragma unroll
  for (int e = 0; e < NE; ++e) {
    const vf4* wr = (const vf4*)(lgate + e * DIN);
#pragma unroll
    for (int i = 0; i < 4; ++i) {
      vf4 w = wr[lane + 64 * i];
      za[e] += xa[i].x * w.x + xa[i].y * w.y + xa[i].z * w.z + xa[i].w * w.w;
      zb[e] += xb[i].x * w.x + xb[i].y * w.y + xb[i].z * w.z + xb[i].w * w.w;
    }
  }
#pragma unroll
  for (int e = 0; e < NE; ++e) {
    float bias = gate_b[e] + expert_biases[e];
    za[e] = wredsum(za[e]) + bias;
    zb[e] = wredsum(zb[e]) + bias;
  }

  // ---- top-2 on logits (sigmoid monotone; strict > matches lax.top_k ties) ----
  int e0a = 0; float z0a = za[0];
#pragma unroll
  for (int e = 1; e < NE; ++e) if (za[e] > z0a) { z0a = za[e]; e0a = e; }
  int e1a = (e0a == 0) ? 1 : 0; float z1a = za[e1a];
#pragma unroll
  for (int e = 0; e < NE; ++e) if (e != e0a && za[e] > z1a) { z1a = za[e]; e1a = e; }

  int e0b = 0; float z0b = zb[0];
#pragma unroll
  for (int e = 1; e < NE; ++e) if (zb[e] > z0b) { z0b = zb[e]; e0b = e; }
  int e1b = (e0b == 0) ? 1 : 0; float z1b = zb[e1b];
#pragma unroll
  for (int e = 0; e < NE; ++e) if (e != e0b && zb[e] > z1b) { z1b = zb[e]; e1b = e; }

  float p0a = 1.f / (1.f + expf(-z0a));
  float p1a = 1.f / (1.f + expf(-z1a));
  float sa = 1.f / (p0a + p1a);
  float w0a = p0a * sa, w1a = p1a * sa;

  float p0b = 1.f / (1.f + expf(-z0b));
  float p1b = 1.f / (1.f + expf(-z1b));
  float sb = 1.f / (p0b + p1b);
  float w0b = p0b * sb, w1b = p1b * sb;

  // ---- value dots from LDS-resident bf16 rows (no global gather) ----
  const ushort4* ra0 = (const ushort4*)lexp + e0a * 256;        // w[e0][0][:]
  const ushort4* ra1 = (const ushort4*)lexp + (8 + e1a) * 256;  // w[e1][1][:]
  const ushort4* rb0 = (const ushort4*)lexp + e0b * 256;
  const ushort4* rb1 = (const ushort4*)lexp + (8 + e1b) * 256;

  float d0a = 0.f, d1a = 0.f, d0b = 0.f, d1b = 0.f;
#pragma unroll
  for (int i = 0; i < 4; ++i) {
    ushort4 a0 = ra0[lane + 64 * i];
    ushort4 a1 = ra1[lane + 64 * i];
    ushort4 b0 = rb0[lane + 64 * i];
    ushort4 b1 = rb1[lane + 64 * i];
    d0a += xa[i].x * bf2f(a0.x) + xa[i].y * bf2f(a0.y) + xa[i].z * bf2f(a0.z) + xa[i].w * bf2f(a0.w);
    d1a += xa[i].x * bf2f(a1.x) + xa[i].y * bf2f(a1.y) + xa[i].z * bf2f(a1.z) + xa[i].w * bf2f(a1.w);
    d0b += xb[i].x * bf2f(b0.x) + xb[i].y * bf2f(b0.y) + xb[i].z * bf2f(b0.z) + xb[i].w * bf2f(b0.w);
    d1b += xb[i].x * bf2f(b1.x) + xb[i].y * bf2f(b1.y) + xb[i].z * bf2f(b1.z) + xb[i].w * bf2f(b1.w);
  }
  d0a = wredsum(d0a) + expert_b[e0a * DOUT + 0];
  d1a = wredsum(d1a) + expert_b[e1a * DOUT + 1];
  d0b = wredsum(d0b) + expert_b[e0b * DOUT + 0];
  d1b = wredsum(d1b) + expert_b[e1b * DOUT + 1];

  float ova = d0a * w0a + d1a * w1a;
  float ovb = d0b * w0b + d1b * w1b;

  // ---- broadcast store: out[t,:] = weighted scalar ----
  vf4 va = {ova, ova, ova, ova};
  vf4 vb = {ovb, ovb, ovb, ovb};
  vf4* oa = (vf4*)(out + (size_t)t0 * DOUT);
  vf4* ob = (vf4*)(out + (size_t)t1 * DOUT);
#pragma unroll
  for (int i = 0; i < 4; ++i) {
    oa[lane + 64 * i] = va;
    ob[lane + 64 * i] = vb;
  }

  if (lane == 0) {
    out_idx[t0 * 2 + 0] = (float)e0a;
    out_idx[t0 * 2 + 1] = (float)e1a;
    out_idx[t1 * 2 + 0] = (float)e0b;
    out_idx[t1 * 2 + 1] = (float)e1b;
  }
}

extern "C" void kernel_launch(void* const* d_in, const int* in_sizes, int n_in,
                              void* d_out, int out_size, void* d_ws, size_t ws_size,
                              hipStream_t stream) {
  const float* x             = (const float*)d_in[0];
  const float* gate_w        = (const float*)d_in[1];
  const float* gate_b        = (const float*)d_in[2];
  const float* expert_biases = (const float*)d_in[3];
  const float* expert_w      = (const float*)d_in[4];
  const float* expert_b      = (const float*)d_in[5];

  float* out     = (float*)d_out;
  float* out_idx = out + (size_t)TOKENS * DOUT;  // second tuple output, flat-concatenated

  // 512 blocks x 512 threads: 8 waves/block, 2 tokens/wave -> 8192 tokens exact.
  moe_fused<<<dim3(512), dim3(512), 0, stream>>>(
      x, gate_w, gate_b, expert_biases, expert_w, expert_b, out, out_idx);
}

// Round 5
// 113.431 us; speedup vs baseline: 1.1529x; 1.1529x over previous
//
#include <hip/hip_runtime.h>
#include <math.h>

// Problem constants: B=4, S=2048, D_IN=1024, D_OUT=1024, E=8, K=2
#define TOKENS 8192
#define DIN    1024
#define DOUT   1024
#define NE     8

typedef float vf4 __attribute__((ext_vector_type(4)));

// One wave per token: 8192 waves = 1024 blocks x 512 threads -> 4 blocks/CU,
// the full 32 waves/CU resident (LDS 32 KB/block * 4 = 128 <= 160 KB).
// All latency-critical phases are stage-major so independent ops issue
// back-to-back (few latency exposures) instead of dependent chains.
__global__ __launch_bounds__(512, 4) void moe_fused(
    const float* __restrict__ x,             // [TOKENS][DIN]
    const float* __restrict__ gate_w,        // [NE][DIN]
    const float* __restrict__ gate_b,        // [NE]
    const float* __restrict__ expert_biases, // [NE]
    const float* __restrict__ expert_w,      // [NE][DOUT][DIN]
    const float* __restrict__ expert_b,      // [NE][DOUT]
    float* __restrict__ out,                 // [TOKENS][DOUT]
    float* __restrict__ out_idx) {           // [TOKENS][2] (indices as f32)
  __shared__ float lgate[NE * DIN];  // 32 KB f32 (selection must be f32-exact)

  // ---- stage gate_w into LDS (2048 vf4 over 512 threads) ----
  {
    const vf4* src = (const vf4*)gate_w;
    vf4* dst = (vf4*)lgate;
#pragma unroll
    for (int i = 0; i < 4; ++i)
      dst[threadIdx.x + 512 * i] = src[threadIdx.x + 512 * i];
  }

  const int t    = blockIdx.x * 8 + (threadIdx.x >> 6);  // token == wave id
  const int lane = threadIdx.x & 63;

  // ---- issue x loads BEFORE the barrier: HBM latency hides under the
  //      s_waitcnt vmcnt(0)+s_barrier the compiler emits for __syncthreads ----
  vf4 xa[4];
  const vf4* xr = (const vf4*)(x + (size_t)t * DIN);
#pragma unroll
  for (int i = 0; i < 4; ++i) xa[i] = xr[lane + 64 * i];

  __syncthreads();

  // ---- gate logits, stage-major: per segment i issue all 8 experts' reads ----
  float za[NE];
#pragma unroll
  for (int e = 0; e < NE; ++e) za[e] = 0.f;
#pragma unroll
  for (int i = 0; i < 4; ++i) {
    vf4 w[NE];
#pragma unroll
    for (int e = 0; e < NE; ++e)
      w[e] = ((const vf4*)(lgate + e * DIN))[lane + 64 * i];
#pragma unroll
    for (int e = 0; e < NE; ++e)
      za[e] += xa[i].x * w[e].x + xa[i].y * w[e].y + xa[i].z * w[e].z + xa[i].w * w[e].w;
  }

  // ---- butterfly reduction, stage-major: 8 independent shuffles per stage ----
#pragma unroll
  for (int off = 32; off > 0; off >>= 1) {
    float tmp[NE];
#pragma unroll
    for (int e = 0; e < NE; ++e) tmp[e] = __shfl_xor(za[e], off, 64);
#pragma unroll
    for (int e = 0; e < NE; ++e) za[e] += tmp[e];
  }
#pragma unroll
  for (int e = 0; e < NE; ++e) za[e] += gate_b[e] + expert_biases[e];

  // ---- top-2 on logits (sigmoid monotone -> identical indices & tie order) ----
  int e0 = 0; float z0 = za[0];
#pragma unroll
  for (int e = 1; e < NE; ++e) if (za[e] > z0) { z0 = za[e]; e0 = e; }
  int e1 = (e0 == 0) ? 1 : 0; float z1 = za[e1];
#pragma unroll
  for (int e = 0; e < NE; ++e) if (e != e0 && za[e] > z1) { z1 = za[e]; e1 = e; }

  // ---- issue both expert value rows (L2-hot 64 KB working set) + biases ----
  const vf4* r0 = (const vf4*)(expert_w + (size_t)e0 * (DOUT * DIN));        // w[e0][0][:]
  const vf4* r1 = (const vf4*)(expert_w + (size_t)e1 * (DOUT * DIN) + DIN);  // w[e1][1][:]
  vf4 wa[4], wb[4];
#pragma unroll
  for (int i = 0; i < 4; ++i) { wa[i] = r0[lane + 64 * i]; wb[i] = r1[lane + 64 * i]; }
  float b0 = expert_b[e0 * DOUT + 0];
  float b1 = expert_b[e1 * DOUT + 1];

  // sigmoid + normalize (overlaps the value-row loads)
  float p0 = 1.f / (1.f + expf(-z0));
  float p1 = 1.f / (1.f + expf(-z1));
  float s  = 1.f / (p0 + p1);
  float w0 = p0 * s, w1 = p1 * s;

  // ---- value dots ----
  float d0 = 0.f, d1 = 0.f;
#pragma unroll
  for (int i = 0; i < 4; ++i) {
    d0 += xa[i].x * wa[i].x + xa[i].y * wa[i].y + xa[i].z * wa[i].z + xa[i].w * wa[i].w;
    d1 += xa[i].x * wb[i].x + xa[i].y * wb[i].y + xa[i].z * wb[i].z + xa[i].w * wb[i].w;
  }
#pragma unroll
  for (int off = 32; off > 0; off >>= 1) {
    float t0 = __shfl_xor(d0, off, 64);
    float t1 = __shfl_xor(d1, off, 64);
    d0 += t0; d1 += t1;
  }
  d0 += b0; d1 += b1;

  float ov = d0 * w0 + d1 * w1;

  // ---- broadcast store: out[t,:] = weighted scalar (4 KB row / wave) ----
  vf4 v = {ov, ov, ov, ov};
  vf4* orow = (vf4*)(out + (size_t)t * DOUT);
#pragma unroll
  for (int i = 0; i < 4; ++i) orow[lane + 64 * i] = v;

  if (lane == 0) {
    out_idx[t * 2 + 0] = (float)e0;
    out_idx[t * 2 + 1] = (float)e1;
  }
}

extern "C" void kernel_launch(void* const* d_in, const int* in_sizes, int n_in,
                              void* d_out, int out_size, void* d_ws, size_t ws_size,
                              hipStream_t stream) {
  const float* x             = (const float*)d_in[0];
  const float* gate_w        = (const float*)d_in[1];
  const float* gate_b        = (const float*)d_in[2];
  const float* expert_biases = (const float*)d_in[3];
  const float* expert_w      = (const float*)d_in[4];
  const float* expert_b      = (const float*)d_in[5];

  float* out     = (float*)d_out;
  float* out_idx = out + (size_t)TOKENS * DOUT;  // second tuple output, flat-concatenated

  // 1024 blocks x 512 threads (8 waves) x 1 token/wave = 8192 tokens exact.
  moe_fused<<<dim3(1024), dim3(512), 0, stream>>>(
      x, gate_w, gate_b, expert_biases, expert_w, expert_b, out, out_idx);
}